// Round 8
// baseline (192.618 us; speedup 1.0000x reference)
//
#include <hip/hip_runtime.h>
#include <hip/hip_bf16.h>
#include <stdint.h>

#define NN 40000
#define EE 640000
#define HD 128
#define TDIM 128
#define TB 128
#define NTILES (EE / TB)   // 5000
#define GRID 768           // persistent: 3 blocks/CU (LDS-bound), 24 waves/CU

typedef short  s16x8 __attribute__((ext_vector_type(8)));
typedef float  f32x4 __attribute__((ext_vector_type(4)));
typedef unsigned int u32x4 __attribute__((ext_vector_type(4)));
typedef unsigned short u16;
typedef unsigned int   u32;

__device__ __forceinline__ u32 cvtpk(float lo, float hi) {
  u32 r; asm("v_cvt_pk_bf16_f32 %0, %1, %2" : "=v"(r) : "v"(lo), "v"(hi)); return r;
}
__device__ __forceinline__ float b2f_lo(u32 w){ union{u32 u; float f;} x; x.u = w << 16; return x.f; }
__device__ __forceinline__ float b2f_hi(u32 w){ union{u32 u; float f;} x; x.u = w & 0xffff0000u; return x.f; }
__device__ __forceinline__ u16 f2b(float f) {
  union { float f; u32 u; } x; x.f = f;
  u32 r = x.u + 0x7fffu + ((x.u >> 16) & 1u);
  return (u16)(r >> 16);
}

// ---- FiLM params: film[0:128]=shift, film[128:256]=1+scale ----
__global__ void prep_film_kernel(const float* __restrict__ te, const float* __restrict__ tW,
                                 const float* __restrict__ tb, float* __restrict__ film) {
  __shared__ float s[TDIM];
  int t = threadIdx.x;
  if (t < TDIM) { float v = te[t]; s[t] = v * __builtin_amdgcn_rcpf(1.f + __expf(-v)); }
  __syncthreads();
  float acc = tb[t];
  #pragma unroll 8
  for (int k = 0; k < TDIM; ++k) acc = fmaf(s[k], tW[k * 256 + t], acc);
  film[t] = (t >= 128) ? (1.f + acc) : acc;
}

// ---- wPt[256][128]: wPt[c][k] = iW[(c>>7)*128 + k][c&127] ----
__global__ void prep_wpt_kernel(const float* __restrict__ iW, u16* __restrict__ wPt) {
  int idx = blockIdx.x * 256 + threadIdx.x;
  if (idx < 256 * 128) {
    int c = idx >> 7, k = idx & 127;
    wPt[idx] = f2b(iW[((c >> 7) * 128 + k) * HD + (c & 127)]);
  }
}

// ---- GEMM1 weights in exact LDS fragment-read order:
//      idx = ks*4096 + lg*1024 + n*128 + l15*8 + j
//      value = iW[256 + ks*32+lg*8+j][n*16+l15]  ----
__global__ void prep_ad_kernel(const float* __restrict__ iW, u16* __restrict__ wadWt) {
  int idx = blockIdx.x * 256 + threadIdx.x;
  if (idx < 8192) {
    int j = idx & 7, l15 = (idx >> 3) & 15, n = (idx >> 7) & 7, lg = (idx >> 10) & 3, ks = idx >> 12;
    int row = n * 16 + l15;
    int k = ks * 32 + lg * 8 + j;
    wadWt[idx] = f2b(iW[(256 + k) * HD + row]);
  }
}

// ---- GEMM2 weights, k-permuted (register-local B) AND fragment-ordered:
//      idx = kq*4096 + lg*1024 + n*128 + l15*8 + j
//      ch  = (2*kq + (j>>2))*16 + lg*4 + (j&3)   (k-slot -> semantic channel)
//      value = (1+scale[ch]) * c1W[ch][n*16+l15] ----
__global__ void prep_c1w_kernel(const float* __restrict__ c1W, const float* __restrict__ film,
                                u16* __restrict__ c1Wt) {
  int idx = blockIdx.x * 256 + threadIdx.x;
  if (idx < 16384) {
    int j = idx & 7, l15 = (idx >> 3) & 15, n = (idx >> 7) & 7, lg = (idx >> 10) & 3, kq = idx >> 12;
    int row = n * 16 + l15;
    int ch = (kq * 2 + (j >> 2)) * 16 + lg * 4 + (j & 3);
    c1Wt[idx] = f2b(film[128 + ch] * c1W[ch * HD + row]);
  }
}

// ---- biasp[c] = c1b[c] + sum_k shift[k] * c1W[k][c] ----
__global__ void prep_bias_kernel(const float* __restrict__ c1b, const float* __restrict__ film,
                                 const float* __restrict__ c1W, float* __restrict__ biasp) {
  int t = threadIdx.x;  // 0..127
  float acc = c1b[t];
  #pragma unroll 8
  for (int k = 0; k < 128; ++k) acc = fmaf(film[k], c1W[k * HD + t], acc);
  biasp[t] = acc;
}

// ---- P[node][256] bf16 in fragment-permuted order ----
__global__ __launch_bounds__(256) void prep_P_kernel(const float* __restrict__ h,
                                                     const u16* __restrict__ wPt,
                                                     const float* __restrict__ ib,
                                                     u16* __restrict__ P) {
  __shared__ u16 sWp[256][136];
  __shared__ float sib[HD];
  int t = threadIdx.x;
  if (t < 128) sib[t] = ib[t];
  {
    const u16* src = wPt + t * 128;
    #pragma unroll
    for (int i = 0; i < 16; ++i)
      *(uint4*)&sWp[t][i * 8] = *(const uint4*)(src + i * 8);
  }
  int wave = t >> 6, lane = t & 63, l15 = lane & 15, lg = lane >> 4;
  int node = blockIdx.x * 64 + wave * 16 + l15;
  uint4 hb[4];
  const float* hr = h + (size_t)node * HD + lg * 8;
  #pragma unroll
  for (int c = 0; c < 4; ++c) {
    float4 a = *(const float4*)(hr + c * 32);
    float4 b = *(const float4*)(hr + c * 32 + 4);
    hb[c].x = cvtpk(a.x, a.y); hb[c].y = cvtpk(a.z, a.w);
    hb[c].z = cvtpk(b.x, b.y); hb[c].w = cvtpk(b.z, b.w);
  }
  __syncthreads();
  f32x4 acc[16];
  #pragma unroll
  for (int n = 0; n < 16; ++n) acc[n] = (f32x4){0.f, 0.f, 0.f, 0.f};
  #pragma unroll
  for (int c = 0; c < 4; ++c) {
    s16x8 bF = *(const s16x8*)&hb[c];
    #pragma unroll
    for (int n = 0; n < 16; ++n) {
      s16x8 aF = *(const s16x8*)&sWp[n * 16 + l15][c * 32 + lg * 8];
      acc[n] = __builtin_amdgcn_mfma_f32_16x16x32_bf16(aF, bF, acc[n], 0, 0, 0);
    }
  }
  u16* dst = P + (size_t)node * 256;
  #pragma unroll
  for (int n = 0; n < 16; ++n) {
    int cb = n * 16 + lg * 4;
    float a0 = acc[n][0], a1 = acc[n][1], a2 = acc[n][2], a3 = acc[n][3];
    if (n < 8) { a0 += sib[cb]; a1 += sib[cb + 1]; a2 += sib[cb + 2]; a3 += sib[cb + 3]; }
    int slot = (n < 8) ? (lg * 32 + n * 4) : (128 + lg * 32 + (n - 8) * 4);
    uint2 wv; wv.x = cvtpk(a0, a1); wv.y = cvtpk(a2, a3);
    *(uint2*)(dst + slot) = wv;
  }
}

// ---- out = pos ----
__global__ void copy_pos_kernel(const float* __restrict__ pos, float* __restrict__ out) {
  int i = blockIdx.x * 256 + threadIdx.x;
  if (i < NN * 3) out[i] = pos[i];
}

// ---- small prefetch state ----
struct PfS {
  int ri, ci;
  float4 a0, a1, d0, d1;
  float p0x, p0y, p0z, p1x, p1y, p1z;
};

// ---- persistent fused edge kernel: 8 waves/block for TLP ----
__global__ __launch_bounds__(512, 6) void edge_kernel(
    const float* __restrict__ pos,
    const float* __restrict__ edge_attr,
    const float* __restrict__ dist,
    const float* __restrict__ c2w,
    const float* __restrict__ cn_scale,
    const int*   __restrict__ eidx,
    const u16*   __restrict__ P,       // [N][256] bf16, fragment-permuted
    const u16*   __restrict__ wadWt,   // [8192]  fragment-ordered GEMM1 weights
    const u16*   __restrict__ c1Wt,    // [16384] fragment-ordered, k-permuted GEMM2 weights
    const float* __restrict__ biasp,   // [128]
    float*       __restrict__ out)
{
  __shared__ u16   sW1[8192];    // 16 KB
  __shared__ u16   sW2[16384];   // 32 KB
  __shared__ float sC1b[HD];
  __shared__ float sC2w[HD];

  const int t    = threadIdx.x;
  const int lane = t & 63;
  const int wave = t >> 6;        // 0..7
  const int l15  = lane & 15;
  const int lg   = lane >> 4;
  const int wv   = wave * 16 + l15;   // edge offset in tile, 0..127

  if (t < HD) { sC1b[t] = biasp[t]; sC2w[t] = c2w[t]; }
  {
    const uint4* s1 = (const uint4*)wadWt;   // 1024 uint4
    uint4* d1 = (uint4*)sW1;
    #pragma unroll
    for (int i = 0; i < 2; ++i) d1[t + i * 512] = s1[t + i * 512];
    const uint4* s2 = (const uint4*)c1Wt;    // 2048 uint4
    uint4* d2 = (uint4*)sW2;
    #pragma unroll
    for (int i = 0; i < 4; ++i) d2[t + i * 512] = s2[t + i * 512];
  }

  const float cns = cn_scale[0];
  const int bbase = lg * 2048 + l15 * 16;   // byte base within each 8KB k-panel

  auto pf_idx_ad = [&](PfS& p, int tile) {
    int e = tile * TB + wv;
    p.ri = eidx[e];
    p.ci = eidx[EE + e];
    const float* pa = edge_attr + (size_t)e * 32 + lg * 8;
    const float* pd = dist      + (size_t)e * 32 + lg * 8;
    p.a0 = *(const float4*)(pa); p.a1 = *(const float4*)(pa + 4);
    p.d0 = *(const float4*)(pd); p.d1 = *(const float4*)(pd + 4);
  };
  auto pf_pos = [&](PfS& p) {
    p.p0x = pos[p.ri * 3 + 0]; p.p0y = pos[p.ri * 3 + 1]; p.p0z = pos[p.ri * 3 + 2];
    p.p1x = pos[p.ci * 3 + 0]; p.p1y = pos[p.ci * 3 + 1]; p.p1z = pos[p.ci * 3 + 2];
  };

  PfS A, B;
  pf_idx_ad(A, blockIdx.x);
  pf_pos(A);

  __syncthreads();   // only barrier: weights + consts visible

  for (int tile = blockIdx.x; tile < NTILES; tile += GRID) {
    int tn = tile + GRID; if (tn >= NTILES) tn = tile;

    // (1) current tile's P gathers — issued first, waited at combine
    uint4 pra0, pra1, pra2, pra3, pca0, pca1, pca2, pca3;
    {
      const u16* pr = P + (size_t)A.ri * 256 + lg * 32;
      const u16* pc = P + (size_t)A.ci * 256 + 128 + lg * 32;
      pra0 = *(const uint4*)(pr);      pra1 = *(const uint4*)(pr + 8);
      pra2 = *(const uint4*)(pr + 16); pra3 = *(const uint4*)(pr + 24);
      pca0 = *(const uint4*)(pc);      pca1 = *(const uint4*)(pc + 8);
      pca2 = *(const uint4*)(pc + 16); pca3 = *(const uint4*)(pc + 24);
    }
    // (2) next tile's independent loads — in flight across this tile
    pf_idx_ad(B, tn);

    // (3) GEMM1: Q = [attr|dist] @ iW_ad, all-immediate-offset LDS reads
    uint4 ef0, ef1;
    ef0.x = cvtpk(A.a0.x, A.a0.y); ef0.y = cvtpk(A.a0.z, A.a0.w);
    ef0.z = cvtpk(A.a1.x, A.a1.y); ef0.w = cvtpk(A.a1.z, A.a1.w);
    ef1.x = cvtpk(A.d0.x, A.d0.y); ef1.y = cvtpk(A.d0.z, A.d0.w);
    ef1.z = cvtpk(A.d1.x, A.d1.y); ef1.w = cvtpk(A.d1.z, A.d1.w);

    f32x4 acc[8];
    #pragma unroll
    for (int n = 0; n < 8; ++n) acc[n] = (f32x4){0.f, 0.f, 0.f, 0.f};
    #pragma unroll
    for (int ks = 0; ks < 2; ++ks) {
      s16x8 bF = (ks == 0) ? *(const s16x8*)&ef0 : *(const s16x8*)&ef1;
      #pragma unroll
      for (int n = 0; n < 8; ++n) {
        s16x8 aF = *(const s16x8*)((const char*)sW1 + ks * 8192 + bbase + n * 256);
        acc[n] = __builtin_amdgcn_mfma_f32_16x16x32_bf16(aF, bF, acc[n], 0, 0, 0);
      }
    }

    // (4) x = Q + P_r + P_c; LN stats in registers (waits on P only)
    float x[8][4];
    float sum = 0.f, sq = 0.f;
    #pragma unroll
    for (int i = 0; i < 4; ++i) {
      uint4 pa = (i == 0) ? pra0 : (i == 1) ? pra1 : (i == 2) ? pra2 : pra3;
      uint4 pc = (i == 0) ? pca0 : (i == 1) ? pca1 : (i == 2) ? pca2 : pca3;
      float v0 = acc[2*i][0] + b2f_lo(pa.x) + b2f_lo(pc.x);
      float v1 = acc[2*i][1] + b2f_hi(pa.x) + b2f_hi(pc.x);
      float v2 = acc[2*i][2] + b2f_lo(pa.y) + b2f_lo(pc.y);
      float v3 = acc[2*i][3] + b2f_hi(pa.y) + b2f_hi(pc.y);
      float v4 = acc[2*i+1][0] + b2f_lo(pa.z) + b2f_lo(pc.z);
      float v5 = acc[2*i+1][1] + b2f_hi(pa.z) + b2f_hi(pc.z);
      float v6 = acc[2*i+1][2] + b2f_lo(pa.w) + b2f_lo(pc.w);
      float v7 = acc[2*i+1][3] + b2f_hi(pa.w) + b2f_hi(pc.w);
      x[2*i][0]=v0; x[2*i][1]=v1; x[2*i][2]=v2; x[2*i][3]=v3;
      x[2*i+1][0]=v4; x[2*i+1][1]=v5; x[2*i+1][2]=v6; x[2*i+1][3]=v7;
      sum += v0+v1+v2+v3+v4+v5+v6+v7;
      sq = fmaf(v0,v0,sq); sq = fmaf(v1,v1,sq); sq = fmaf(v2,v2,sq); sq = fmaf(v3,v3,sq);
      sq = fmaf(v4,v4,sq); sq = fmaf(v5,v5,sq); sq = fmaf(v6,v6,sq); sq = fmaf(v7,v7,sq);
    }
    sum += __shfl_xor(sum, 16); sum += __shfl_xor(sum, 32);
    sq  += __shfl_xor(sq,  16); sq  += __shfl_xor(sq,  32);
    float mean = sum * (1.f / 128.f);
    float var  = sq  * (1.f / 128.f) - mean * mean;
    float LA = rsqrtf(var + 1e-6f);
    float LB = -mean * LA;

    union { uint2 u2[8]; u32 w[16]; } xb;
    #pragma unroll
    for (int n = 0; n < 8; ++n) {
      float y0 = fmaf(x[n][0], LA, LB);
      float y1 = fmaf(x[n][1], LA, LB);
      float y2 = fmaf(x[n][2], LA, LB);
      float y3 = fmaf(x[n][3], LA, LB);
      xb.u2[n].x = cvtpk(y0, y1);
      xb.u2[n].y = cvtpk(y2, y3);
    }

    // (5) GEMM2: B from registers, A via immediate-offset LDS
    f32x4 acc2[8];
    #pragma unroll
    for (int n = 0; n < 8; ++n) acc2[n] = (f32x4){0.f, 0.f, 0.f, 0.f};
    #pragma unroll
    for (int kq = 0; kq < 4; ++kq) {
      u32x4 xw = { xb.w[4*kq], xb.w[4*kq+1], xb.w[4*kq+2], xb.w[4*kq+3] };
      s16x8 xF = __builtin_bit_cast(s16x8, xw);
      #pragma unroll
      for (int n = 0; n < 8; ++n) {
        s16x8 aF = *(const s16x8*)((const char*)sW2 + kq * 8192 + bbase + n * 256);
        acc2[n] = __builtin_amdgcn_mfma_f32_16x16x32_bf16(aF, xF, acc2[n], 0, 0, 0);
      }
    }

    // (6) next tile's pos loads — eidx long landed; consumed next iteration
    pf_pos(B);

    // (7) silu -> dot(c2W) -> tanh -> scatter
    float z = 0.f;
    #pragma unroll
    for (int n = 0; n < 8; ++n) {
      int cb = n * 16 + lg * 4;
      f32x4 cb4 = *(const f32x4*)&sC1b[cb];
      f32x4 cw4 = *(const f32x4*)&sC2w[cb];
      #pragma unroll
      for (int r = 0; r < 4; ++r) {
        float y = acc2[n][r] + cb4[r];
        float s = y * __builtin_amdgcn_rcpf(1.f + __expf(-y));
        z = fmaf(s, cw4[r], z);
      }
    }
    z += __shfl_xor(z, 16); z += __shfl_xor(z, 32);

    if (lg < 3) {
      float zc = fminf(fmaxf(z, -15.f), 15.f);
      float ez = __expf(2.f * zc);
      float inv = (ez - 1.f) * __builtin_amdgcn_rcpf(ez + 1.f);
      float dx = A.p0x - A.p1x, dy = A.p0y - A.p1y, dz = A.p0z - A.p1z;
      float nrm = sqrtf(fmaf(dx, dx, fmaf(dy, dy, dz * dz)));
      float sc  = cns * inv * __builtin_amdgcn_rcpf(fmaxf(nrm, 1e-8f));
      float d   = (lg == 0) ? dx : ((lg == 1) ? dy : dz);
      atomicAdd(out + (size_t)A.ri * 3 + lg, d * sc);
    }

    A = B;   // static copy
  }
}

extern "C" void kernel_launch(void* const* d_in, const int* in_sizes, int n_in,
                              void* d_out, int out_size, void* d_ws, size_t ws_size,
                              hipStream_t stream) {
  const float* h         = (const float*)d_in[0];
  const float* pos       = (const float*)d_in[1];
  const float* edge_attr = (const float*)d_in[2];
  const float* dist      = (const float*)d_in[3];
  const float* te        = (const float*)d_in[4];
  const float* tW        = (const float*)d_in[5];
  const float* tb        = (const float*)d_in[6];
  const float* iW        = (const float*)d_in[7];
  const float* ib        = (const float*)d_in[8];
  const float* c1W       = (const float*)d_in[9];
  const float* c1b       = (const float*)d_in[10];
  const float* c2W       = (const float*)d_in[11];
  const float* cn        = (const float*)d_in[12];
  const int*   eidx      = (const int*)d_in[13];
  float* out = (float*)d_out;

  char* ws = (char*)d_ws;
  u16*   P      = (u16*)(ws);                    // 40000*256*2 = 20,480,000 B
  u16*   wPt    = (u16*)(ws + 20480000);         // 65,536 B
  u16*   wadWt  = (u16*)(ws + 20545536);         // 16,384 B
  u16*   c1Wt   = (u16*)(ws + 20561920);         // 32,768 B
  float* film   = (float*)(ws + 20594688);       // 1,024 B
  float* biasp  = (float*)(ws + 20595712);       // 512 B

  hipLaunchKernelGGL(prep_film_kernel, dim3(1),   dim3(256), 0, stream, te, tW, tb, film);
  hipLaunchKernelGGL(prep_wpt_kernel,  dim3(128), dim3(256), 0, stream, iW, wPt);
  hipLaunchKernelGGL(prep_ad_kernel,   dim3(32),  dim3(256), 0, stream, iW, wadWt);
  hipLaunchKernelGGL(prep_c1w_kernel,  dim3(64),  dim3(256), 0, stream, c1W, film, c1Wt);
  hipLaunchKernelGGL(prep_bias_kernel, dim3(1),   dim3(128), 0, stream, c1b, film, c1W, biasp);
  hipLaunchKernelGGL(prep_P_kernel,    dim3(625), dim3(256), 0, stream, h, wPt, ib, P);
  hipLaunchKernelGGL(copy_pos_kernel,  dim3(469), dim3(256), 0, stream, pos, out);
  hipLaunchKernelGGL(edge_kernel,      dim3(GRID), dim3(512), 0, stream,
                     pos, edge_attr, dist, c2W, cn, eidx,
                     P, wadWt, c1Wt, biasp, out);
}

// Round 9
// 125.340 us; speedup vs baseline: 1.5368x; 1.5368x over previous
//
#include <hip/hip_runtime.h>
#include <hip/hip_bf16.h>
#include <stdint.h>

#define NN 40000
#define EE 640000
#define HD 128
#define TDIM 128
#define TB 128
#define NTILES (EE / TB)   // 5000
#define GRID 512           // persistent: 2 blocks/CU, 16 waves/CU

typedef short  s16x8 __attribute__((ext_vector_type(8)));
typedef float  f32x4 __attribute__((ext_vector_type(4)));
typedef unsigned int u32x4 __attribute__((ext_vector_type(4)));
typedef unsigned short u16;
typedef unsigned int   u32;

__device__ __forceinline__ u32 cvtpk(float lo, float hi) {
  u32 r; asm("v_cvt_pk_bf16_f32 %0, %1, %2" : "=v"(r) : "v"(lo), "v"(hi)); return r;
}
__device__ __forceinline__ float b2f_lo(u32 w){ union{u32 u; float f;} x; x.u = w << 16; return x.f; }
__device__ __forceinline__ float b2f_hi(u32 w){ union{u32 u; float f;} x; x.u = w & 0xffff0000u; return x.f; }
__device__ __forceinline__ u16 f2b(float f) {
  union { float f; u32 u; } x; x.f = f;
  u32 r = x.u + 0x7fffu + ((x.u >> 16) & 1u);
  return (u16)(r >> 16);
}

// ---- FiLM params: film[0:128]=shift, film[128:256]=1+scale ----
__global__ void prep_film_kernel(const float* __restrict__ te, const float* __restrict__ tW,
                                 const float* __restrict__ tb, float* __restrict__ film) {
  __shared__ float s[TDIM];
  int t = threadIdx.x;
  if (t < TDIM) { float v = te[t]; s[t] = v * __builtin_amdgcn_rcpf(1.f + __expf(-v)); }
  __syncthreads();
  float acc = tb[t];
  #pragma unroll 8
  for (int k = 0; k < TDIM; ++k) acc = fmaf(s[k], tW[k * 256 + t], acc);
  film[t] = (t >= 128) ? (1.f + acc) : acc;
}

// ---- wPt[256][128]: wPt[c][k] = iW[(c>>7)*128 + k][c&127] ----
__global__ void prep_wpt_kernel(const float* __restrict__ iW, u16* __restrict__ wPt) {
  int idx = blockIdx.x * 256 + threadIdx.x;
  if (idx < 256 * 128) {
    int c = idx >> 7, k = idx & 127;
    wPt[idx] = f2b(iW[((c >> 7) * 128 + k) * HD + (c & 127)]);
  }
}

// ---- GEMM1 weights in exact LDS fragment-read order ----
__global__ void prep_ad_kernel(const float* __restrict__ iW, u16* __restrict__ wadWt) {
  int idx = blockIdx.x * 256 + threadIdx.x;
  if (idx < 8192) {
    int j = idx & 7, l15 = (idx >> 3) & 15, n = (idx >> 7) & 7, lg = (idx >> 10) & 3, ks = idx >> 12;
    int row = n * 16 + l15;
    int k = ks * 32 + lg * 8 + j;
    wadWt[idx] = f2b(iW[(256 + k) * HD + row]);
  }
}

// ---- GEMM2 weights, k-permuted (register-local B) AND fragment-ordered ----
__global__ void prep_c1w_kernel(const float* __restrict__ c1W, const float* __restrict__ film,
                                u16* __restrict__ c1Wt) {
  int idx = blockIdx.x * 256 + threadIdx.x;
  if (idx < 16384) {
    int j = idx & 7, l15 = (idx >> 3) & 15, n = (idx >> 7) & 7, lg = (idx >> 10) & 3, kq = idx >> 12;
    int row = n * 16 + l15;
    int ch = (kq * 2 + (j >> 2)) * 16 + lg * 4 + (j & 3);
    c1Wt[idx] = f2b(film[128 + ch] * c1W[ch * HD + row]);
  }
}

// ---- biasp[c] = c1b[c] + sum_k shift[k] * c1W[k][c] ----
__global__ void prep_bias_kernel(const float* __restrict__ c1b, const float* __restrict__ film,
                                 const float* __restrict__ c1W, float* __restrict__ biasp) {
  int t = threadIdx.x;  // 0..127
  float acc = c1b[t];
  #pragma unroll 8
  for (int k = 0; k < 128; ++k) acc = fmaf(film[k], c1W[k * HD + t], acc);
  biasp[t] = acc;
}

// ---- P[node][256] bf16 in fragment-permuted order ----
__global__ __launch_bounds__(256) void prep_P_kernel(const float* __restrict__ h,
                                                     const u16* __restrict__ wPt,
                                                     const float* __restrict__ ib,
                                                     u16* __restrict__ P) {
  __shared__ u16 sWp[256][136];
  __shared__ float sib[HD];
  int t = threadIdx.x;
  if (t < 128) sib[t] = ib[t];
  {
    const u16* src = wPt + t * 128;
    #pragma unroll
    for (int i = 0; i < 16; ++i)
      *(uint4*)&sWp[t][i * 8] = *(const uint4*)(src + i * 8);
  }
  int wave = t >> 6, lane = t & 63, l15 = lane & 15, lg = lane >> 4;
  int node = blockIdx.x * 64 + wave * 16 + l15;
  uint4 hb[4];
  const float* hr = h + (size_t)node * HD + lg * 8;
  #pragma unroll
  for (int c = 0; c < 4; ++c) {
    float4 a = *(const float4*)(hr + c * 32);
    float4 b = *(const float4*)(hr + c * 32 + 4);
    hb[c].x = cvtpk(a.x, a.y); hb[c].y = cvtpk(a.z, a.w);
    hb[c].z = cvtpk(b.x, b.y); hb[c].w = cvtpk(b.z, b.w);
  }
  __syncthreads();
  f32x4 acc[16];
  #pragma unroll
  for (int n = 0; n < 16; ++n) acc[n] = (f32x4){0.f, 0.f, 0.f, 0.f};
  #pragma unroll
  for (int c = 0; c < 4; ++c) {
    s16x8 bF = *(const s16x8*)&hb[c];
    #pragma unroll
    for (int n = 0; n < 16; ++n) {
      s16x8 aF = *(const s16x8*)&sWp[n * 16 + l15][c * 32 + lg * 8];
      acc[n] = __builtin_amdgcn_mfma_f32_16x16x32_bf16(aF, bF, acc[n], 0, 0, 0);
    }
  }
  u16* dst = P + (size_t)node * 256;
  #pragma unroll
  for (int n = 0; n < 16; ++n) {
    int cb = n * 16 + lg * 4;
    float a0 = acc[n][0], a1 = acc[n][1], a2 = acc[n][2], a3 = acc[n][3];
    if (n < 8) { a0 += sib[cb]; a1 += sib[cb + 1]; a2 += sib[cb + 2]; a3 += sib[cb + 3]; }
    int slot = (n < 8) ? (lg * 32 + n * 4) : (128 + lg * 32 + (n - 8) * 4);
    uint2 wv; wv.x = cvtpk(a0, a1); wv.y = cvtpk(a2, a3);
    *(uint2*)(dst + slot) = wv;
  }
}

// ---- out = pos ----
__global__ void copy_pos_kernel(const float* __restrict__ pos, float* __restrict__ out) {
  int i = blockIdx.x * 256 + threadIdx.x;
  if (i < NN * 3) out[i] = pos[i];
}

// ---- small prefetch state ----
struct PfS {
  int ri, ci;
  float4 a0, a1, d0, d1;
  float p0x, p0y, p0z, p1x, p1y, p1z;
};

// ---- persistent fused edge kernel: depth-1 P prefetch, liveness-ordered epilogue ----
__global__ __launch_bounds__(512, 4) void edge_kernel(
    const float* __restrict__ pos,
    const float* __restrict__ edge_attr,
    const float* __restrict__ dist,
    const float* __restrict__ c2w,
    const float* __restrict__ cn_scale,
    const int*   __restrict__ eidx,
    const u16*   __restrict__ P,       // [N][256] bf16, fragment-permuted
    const u16*   __restrict__ wadWt,   // [8192]  fragment-ordered GEMM1 weights
    const u16*   __restrict__ c1Wt,    // [16384] fragment-ordered, k-permuted GEMM2 weights
    const float* __restrict__ biasp,   // [128]
    float*       __restrict__ out)
{
  __shared__ u16   sW1[8192];    // 16 KB
  __shared__ u16   sW2[16384];   // 32 KB
  __shared__ float sC1b[HD];
  __shared__ float sC2w[HD];

  const int t    = threadIdx.x;
  const int lane = t & 63;
  const int wave = t >> 6;        // 0..7
  const int l15  = lane & 15;
  const int lg   = lane >> 4;
  const int wv   = wave * 16 + l15;   // edge offset in tile, 0..127

  if (t < HD) { sC1b[t] = biasp[t]; sC2w[t] = c2w[t]; }
  {
    const uint4* s1 = (const uint4*)wadWt;   // 1024 uint4
    uint4* d1 = (uint4*)sW1;
    #pragma unroll
    for (int i = 0; i < 2; ++i) d1[t + i * 512] = s1[t + i * 512];
    const uint4* s2 = (const uint4*)c1Wt;    // 2048 uint4
    uint4* d2 = (uint4*)sW2;
    #pragma unroll
    for (int i = 0; i < 4; ++i) d2[t + i * 512] = s2[t + i * 512];
  }

  const float cns = cn_scale[0];
  const int bbase = lg * 2048 + l15 * 16;   // byte base within each 8KB k-panel

  auto pf_idx_ad = [&](PfS& p, int tile) {
    int e = tile * TB + wv;
    p.ri = eidx[e];
    p.ci = eidx[EE + e];
    const float* pa = edge_attr + (size_t)e * 32 + lg * 8;
    const float* pd = dist      + (size_t)e * 32 + lg * 8;
    p.a0 = *(const float4*)(pa); p.a1 = *(const float4*)(pa + 4);
    p.d0 = *(const float4*)(pd); p.d1 = *(const float4*)(pd + 4);
  };
  auto pf_pos = [&](PfS& p) {
    p.p0x = pos[p.ri * 3 + 0]; p.p0y = pos[p.ri * 3 + 1]; p.p0z = pos[p.ri * 3 + 2];
    p.p1x = pos[p.ci * 3 + 0]; p.p1y = pos[p.ci * 3 + 1]; p.p1z = pos[p.ci * 3 + 2];
  };

  PfS A, B;
  pf_idx_ad(A, blockIdx.x);
  pf_pos(A);

  // prologue: P gathers for the first tile (consumed at first combine)
  uint4 pra0, pra1, pra2, pra3, pca0, pca1, pca2, pca3;
  {
    const u16* pr = P + (size_t)A.ri * 256 + lg * 32;
    const u16* pc = P + (size_t)A.ci * 256 + 128 + lg * 32;
    pra0 = *(const uint4*)(pr);      pra1 = *(const uint4*)(pr + 8);
    pra2 = *(const uint4*)(pr + 16); pra3 = *(const uint4*)(pr + 24);
    pca0 = *(const uint4*)(pc);      pca1 = *(const uint4*)(pc + 8);
    pca2 = *(const uint4*)(pc + 16); pca3 = *(const uint4*)(pc + 24);
  }

  __syncthreads();   // only barrier: weights + consts visible

  for (int tile = blockIdx.x; tile < NTILES; tile += GRID) {
    int tn = tile + GRID; if (tn >= NTILES) tn = tile;

    // (1) next tile's independent loads — in flight across this tile
    pf_idx_ad(B, tn);

    // (2) GEMM1: Q = [attr|dist] @ iW_ad, all-immediate-offset LDS reads
    uint4 ef0, ef1;
    ef0.x = cvtpk(A.a0.x, A.a0.y); ef0.y = cvtpk(A.a0.z, A.a0.w);
    ef0.z = cvtpk(A.a1.x, A.a1.y); ef0.w = cvtpk(A.a1.z, A.a1.w);
    ef1.x = cvtpk(A.d0.x, A.d0.y); ef1.y = cvtpk(A.d0.z, A.d0.w);
    ef1.z = cvtpk(A.d1.x, A.d1.y); ef1.w = cvtpk(A.d1.z, A.d1.w);

    f32x4 acc[8];
    #pragma unroll
    for (int n = 0; n < 8; ++n) acc[n] = (f32x4){0.f, 0.f, 0.f, 0.f};
    #pragma unroll
    for (int ks = 0; ks < 2; ++ks) {
      s16x8 bF = (ks == 0) ? *(const s16x8*)&ef0 : *(const s16x8*)&ef1;
      #pragma unroll
      for (int n = 0; n < 8; ++n) {
        s16x8 aF = *(const s16x8*)((const char*)sW1 + ks * 8192 + bbase + n * 256);
        acc[n] = __builtin_amdgcn_mfma_f32_16x16x32_bf16(aF, bF, acc[n], 0, 0, 0);
      }
    }

    // (3) x = Q + P_r + P_c (P prefetched LAST iteration -> latency covered)
    float x[8][4];
    float sum = 0.f, sq = 0.f;
    #pragma unroll
    for (int i = 0; i < 4; ++i) {
      uint4 pa = (i == 0) ? pra0 : (i == 1) ? pra1 : (i == 2) ? pra2 : pra3;
      uint4 pc = (i == 0) ? pca0 : (i == 1) ? pca1 : (i == 2) ? pca2 : pca3;
      float v0 = acc[2*i][0] + b2f_lo(pa.x) + b2f_lo(pc.x);
      float v1 = acc[2*i][1] + b2f_hi(pa.x) + b2f_hi(pc.x);
      float v2 = acc[2*i][2] + b2f_lo(pa.y) + b2f_lo(pc.y);
      float v3 = acc[2*i][3] + b2f_hi(pa.y) + b2f_hi(pc.y);
      float v4 = acc[2*i+1][0] + b2f_lo(pa.z) + b2f_lo(pc.z);
      float v5 = acc[2*i+1][1] + b2f_hi(pa.z) + b2f_hi(pc.z);
      float v6 = acc[2*i+1][2] + b2f_lo(pa.w) + b2f_lo(pc.w);
      float v7 = acc[2*i+1][3] + b2f_hi(pa.w) + b2f_hi(pc.w);
      x[2*i][0]=v0; x[2*i][1]=v1; x[2*i][2]=v2; x[2*i][3]=v3;
      x[2*i+1][0]=v4; x[2*i+1][1]=v5; x[2*i+1][2]=v6; x[2*i+1][3]=v7;
      sum += v0+v1+v2+v3+v4+v5+v6+v7;
      sq = fmaf(v0,v0,sq); sq = fmaf(v1,v1,sq); sq = fmaf(v2,v2,sq); sq = fmaf(v3,v3,sq);
      sq = fmaf(v4,v4,sq); sq = fmaf(v5,v5,sq); sq = fmaf(v6,v6,sq); sq = fmaf(v7,v7,sq);
    }
    sum += __shfl_xor(sum, 16); sum += __shfl_xor(sum, 32);
    sq  += __shfl_xor(sq,  16); sq  += __shfl_xor(sq,  32);
    float mean = sum * (1.f / 128.f);
    float var  = sq  * (1.f / 128.f) - mean * mean;
    float LA = rsqrtf(var + 1e-6f);
    float LB = -mean * LA;

    union { uint2 u2[8]; u32 w[16]; } xb;
    #pragma unroll
    for (int n = 0; n < 8; ++n) {
      float y0 = fmaf(x[n][0], LA, LB);
      float y1 = fmaf(x[n][1], LA, LB);
      float y2 = fmaf(x[n][2], LA, LB);
      float y3 = fmaf(x[n][3], LA, LB);
      xb.u2[n].x = cvtpk(y0, y1);
      xb.u2[n].y = cvtpk(y2, y3);
    }

    // (4) GEMM2: B from registers, A via immediate-offset LDS
    f32x4 acc2[8];
    #pragma unroll
    for (int n = 0; n < 8; ++n) acc2[n] = (f32x4){0.f, 0.f, 0.f, 0.f};
    #pragma unroll
    for (int kq = 0; kq < 4; ++kq) {
      u32x4 xw = { xb.w[4*kq], xb.w[4*kq+1], xb.w[4*kq+2], xb.w[4*kq+3] };
      s16x8 xF = __builtin_bit_cast(s16x8, xw);
      #pragma unroll
      for (int n = 0; n < 8; ++n) {
        s16x8 aF = *(const s16x8*)((const char*)sW2 + kq * 8192 + bbase + n * 256);
        acc2[n] = __builtin_amdgcn_mfma_f32_16x16x32_bf16(aF, xF, acc2[n], 0, 0, 0);
      }
    }

    // (5) silu -> dot(c2W): consumes acc2 NOW (frees 32 regs before next-P gather)
    float z = 0.f;
    #pragma unroll
    for (int n = 0; n < 8; ++n) {
      int cb = n * 16 + lg * 4;
      f32x4 cb4 = *(const f32x4*)&sC1b[cb];
      f32x4 cw4 = *(const f32x4*)&sC2w[cb];
      #pragma unroll
      for (int r = 0; r < 4; ++r) {
        float y = acc2[n][r] + cb4[r];
        float s = y * __builtin_amdgcn_rcpf(1.f + __expf(-y));
        z = fmaf(s, cw4[r], z);
      }
    }
    z += __shfl_xor(z, 16); z += __shfl_xor(z, 32);

    // (6) depth-1 prefetch: next tile's pos + P rows (consumed next combine)
    pf_pos(B);
    uint4 qra0, qra1, qra2, qra3, qca0, qca1, qca2, qca3;
    {
      const u16* pr = P + (size_t)B.ri * 256 + lg * 32;
      const u16* pc = P + (size_t)B.ci * 256 + 128 + lg * 32;
      qra0 = *(const uint4*)(pr);      qra1 = *(const uint4*)(pr + 8);
      qra2 = *(const uint4*)(pr + 16); qra3 = *(const uint4*)(pr + 24);
      qca0 = *(const uint4*)(pc);      qca1 = *(const uint4*)(pc + 8);
      qca2 = *(const uint4*)(pc + 16); qca3 = *(const uint4*)(pc + 24);
    }

    // (7) tanh -> scatter
    if (lg < 3) {
      float zc = fminf(fmaxf(z, -15.f), 15.f);
      float ez = __expf(2.f * zc);
      float inv = (ez - 1.f) * __builtin_amdgcn_rcpf(ez + 1.f);
      float dx = A.p0x - A.p1x, dy = A.p0y - A.p1y, dz = A.p0z - A.p1z;
      float nrm = sqrtf(fmaf(dx, dx, fmaf(dy, dy, dz * dz)));
      float sc  = cns * inv * __builtin_amdgcn_rcpf(fmaxf(nrm, 1e-8f));
      float d   = (lg == 0) ? dx : ((lg == 1) ? dy : dz);
      atomicAdd(out + (size_t)A.ri * 3 + lg, d * sc);
    }

    A = B;
    pra0 = qra0; pra1 = qra1; pra2 = qra2; pra3 = qra3;
    pca0 = qca0; pca1 = qca1; pca2 = qca2; pca3 = qca3;
  }
}

extern "C" void kernel_launch(void* const* d_in, const int* in_sizes, int n_in,
                              void* d_out, int out_size, void* d_ws, size_t ws_size,
                              hipStream_t stream) {
  const float* h         = (const float*)d_in[0];
  const float* pos       = (const float*)d_in[1];
  const float* edge_attr = (const float*)d_in[2];
  const float* dist      = (const float*)d_in[3];
  const float* te        = (const float*)d_in[4];
  const float* tW        = (const float*)d_in[5];
  const float* tb        = (const float*)d_in[6];
  const float* iW        = (const float*)d_in[7];
  const float* ib        = (const float*)d_in[8];
  const float* c1W       = (const float*)d_in[9];
  const float* c1b       = (const float*)d_in[10];
  const float* c2W       = (const float*)d_in[11];
  const float* cn        = (const float*)d_in[12];
  const int*   eidx      = (const int*)d_in[13];
  float* out = (float*)d_out;

  char* ws = (char*)d_ws;
  u16*   P      = (u16*)(ws);                    // 40000*256*2 = 20,480,000 B
  u16*   wPt    = (u16*)(ws + 20480000);         // 65,536 B
  u16*   wadWt  = (u16*)(ws + 20545536);         // 16,384 B
  u16*   c1Wt   = (u16*)(ws + 20561920);         // 32,768 B
  float* film   = (float*)(ws + 20594688);       // 1,024 B
  float* biasp  = (float*)(ws + 20595712);       // 512 B

  hipLaunchKernelGGL(prep_film_kernel, dim3(1),   dim3(256), 0, stream, te, tW, tb, film);
  hipLaunchKernelGGL(prep_wpt_kernel,  dim3(128), dim3(256), 0, stream, iW, wPt);
  hipLaunchKernelGGL(prep_ad_kernel,   dim3(32),  dim3(256), 0, stream, iW, wadWt);
  hipLaunchKernelGGL(prep_c1w_kernel,  dim3(64),  dim3(256), 0, stream, c1W, film, c1Wt);
  hipLaunchKernelGGL(prep_bias_kernel, dim3(1),   dim3(128), 0, stream, c1b, film, c1W, biasp);
  hipLaunchKernelGGL(prep_P_kernel,    dim3(625), dim3(256), 0, stream, h, wPt, ib, P);
  hipLaunchKernelGGL(copy_pos_kernel,  dim3(469), dim3(256), 0, stream, pos, out);
  hipLaunchKernelGGL(edge_kernel,      dim3(GRID), dim3(512), 0, stream,
                     pos, edge_attr, dist, c2W, cn, eidx,
                     P, wadWt, c1Wt, biasp, out);
}